// Round 3
// baseline (235.195 us; speedup 1.0000x reference)
//
#include <hip/hip_runtime.h>
#include <math.h>

#define TOTAL   8192
#define GENES   5000
#define NDS     64          // points per cloud
#define NB      128         // TOTAL / NDS
#define NSHARED 128
#define KC      64          // K-chunk staged in LDS

// ws layout (floats): [0]=gene acc, [1]=cell acc, grams/transpose at GRAM_OFF
#define GRAM_OFF 64

typedef __attribute__((ext_vector_type(8)))  short          short8;
typedef __attribute__((ext_vector_type(4)))  unsigned short ushort4v;
typedef __attribute__((ext_vector_type(16))) float          f32x16;

static __device__ inline unsigned short f2bf(float f) {
    unsigned int u = __builtin_bit_cast(unsigned int, f);
    unsigned int r = (u + 0x7fffu + ((u >> 16) & 1u)) >> 16;   // RNE
    return (unsigned short)r;
}
static __device__ inline float bf2f(unsigned short h) {
    unsigned int u = ((unsigned int)h) << 16;
    return __builtin_bit_cast(float, u);
}

__global__ __launch_bounds__(64) void k_zero(float* ws) {
    ws[threadIdx.x] = 0.0f;
}

// ---------------------------------------------------------------------------
// K1: partial Gram matrices per (batch, K-slice) via bf16 hi/lo split MFMA,
// software-pipelined: next chunk's global loads in flight across compute.
// grams[(b*splitD + c)][m][64*64], m: 0=xy, 1=xx, 2=yy
// ---------------------------------------------------------------------------
__global__ __launch_bounds__(256) void k_gene_gram_mfma(const float* __restrict__ X,
                                                        const float* __restrict__ Y,
                                                        float* __restrict__ grams,
                                                        int splitD, int Dper) {
    const int blk = blockIdx.x;
    const int b = blk / splitD, c = blk % splitD;
    const int d0 = c * Dper;
    const int d1 = min(GENES, d0 + Dper);

    const float* __restrict__ xb = X + (size_t)b * NDS * GENES;
    const float* __restrict__ yb = Y + (size_t)b * NDS * GENES;

    // [m][k] bf16 tiles, element-XOR swizzle  k ^ ((m&7)<<3)  (16B granularity)
    __shared__ __align__(16) unsigned short sXh[NDS * KC], sXl[NDS * KC];
    __shared__ __align__(16) unsigned short sYh[NDS * KC], sYl[NDS * KC];

    const int t    = threadIdx.x;
    const int lane = t & 63;
    const int w    = t >> 6;               // wave 0..3
    const int qr   = w >> 1, qc = w & 1;   // 32x32 output quadrant
    const int lm   = lane & 31;
    const int kh   = (lane >> 5) << 3;     // k-half offset (consistent A/B: cancels)

    const int mr = (qr << 5) + lm;         // A-side row
    const int mc = (qc << 5) + lm;         // B-side row (Gram col)

    // staging-thread geometry
    const int c4  = t & 15;                // float4 column within chunk
    const int mrw = t >> 4;                // base row (16 rows per iteration)

    f32x16 axy = {0,0,0,0,0,0,0,0,0,0,0,0,0,0,0,0};
    f32x16 axx = {0,0,0,0,0,0,0,0,0,0,0,0,0,0,0,0};
    f32x16 ayy = {0,0,0,0,0,0,0,0,0,0,0,0,0,0,0,0};

    float4 rx[4], ry[4];

    // ---- chunk loader: coalesced float4 -> registers (guarded tail) ----
    auto load_chunk = [&](int dd0) {
#pragma unroll
        for (int it = 0; it < 4; ++it) {
            const int m = mrw + (it << 4);
            const int d = dd0 + (c4 << 2);
            float4 vx = {0.f, 0.f, 0.f, 0.f};
            float4 vy = {0.f, 0.f, 0.f, 0.f};
            if (d + 3 < d1) {
                vx = *(const float4*)(xb + (size_t)m * GENES + d);
                vy = *(const float4*)(yb + (size_t)m * GENES + d);
            } else if (d < d1) {
                float* px = &vx.x; float* py = &vy.x;
                for (int q = 0; q < d1 - d; ++q) {
                    px[q] = xb[(size_t)m * GENES + d + q];
                    py[q] = yb[(size_t)m * GENES + d + q];
                }
            }
            rx[it] = vx; ry[it] = vy;
        }
    };

    load_chunk(d0);   // prologue

    for (int dd0 = d0; dd0 < d1; dd0 += KC) {
        // ---- convert current regs to hi/lo bf16 (register-only) ----
        ushort4v xh[4], xl[4], yh[4], yl[4];
#pragma unroll
        for (int it = 0; it < 4; ++it) {
            const float* px = &rx[it].x;
            const float* py = &ry[it].x;
#pragma unroll
            for (int q = 0; q < 4; ++q) {
                const unsigned short h = f2bf(px[q]);
                xh[it][q] = h; xl[it][q] = f2bf(px[q] - bf2f(h));
                const unsigned short g = f2bf(py[q]);
                yh[it][q] = g; yl[it][q] = f2bf(py[q] - bf2f(g));
            }
        }
        // ---- issue next chunk's loads (stay in flight across compute) ----
        if (dd0 + KC < d1) load_chunk(dd0 + KC);

        __syncthreads();   // all waves done reading LDS from previous compute
#pragma unroll
        for (int it = 0; it < 4; ++it) {
            const int m = mrw + (it << 4);
            const int e = m * KC + ((c4 << 2) ^ ((m & 7) << 3));
            *(ushort4v*)&sXh[e] = xh[it];
            *(ushort4v*)&sXl[e] = xl[it];
            *(ushort4v*)&sYh[e] = yh[it];
            *(ushort4v*)&sYl[e] = yl[it];
        }
        __syncthreads();   // LDS ready

        // ---- compute: 4 K=16 steps, 9 MFMAs each into 3 accumulators ----
#pragma unroll
        for (int ks = 0; ks < 4; ++ks) {
            const int kb = (ks << 4) + kh;
            const int er = mr * KC + (kb ^ ((mr & 7) << 3));
            const int ec = mc * KC + (kb ^ ((mc & 7) << 3));
            const short8 xhr = *(const short8*)&sXh[er];
            const short8 xlr = *(const short8*)&sXl[er];
            const short8 yhr = *(const short8*)&sYh[er];
            const short8 ylr = *(const short8*)&sYl[er];
            const short8 xhc = *(const short8*)&sXh[ec];
            const short8 xlc = *(const short8*)&sXl[ec];
            const short8 yhc = *(const short8*)&sYh[ec];
            const short8 ylc = *(const short8*)&sYl[ec];
            axy = __builtin_amdgcn_mfma_f32_32x32x16_bf16(xhr, yhc, axy, 0, 0, 0);
            axx = __builtin_amdgcn_mfma_f32_32x32x16_bf16(xhr, xhc, axx, 0, 0, 0);
            ayy = __builtin_amdgcn_mfma_f32_32x32x16_bf16(yhr, yhc, ayy, 0, 0, 0);
            axy = __builtin_amdgcn_mfma_f32_32x32x16_bf16(xhr, ylc, axy, 0, 0, 0);
            axx = __builtin_amdgcn_mfma_f32_32x32x16_bf16(xhr, xlc, axx, 0, 0, 0);
            ayy = __builtin_amdgcn_mfma_f32_32x32x16_bf16(yhr, ylc, ayy, 0, 0, 0);
            axy = __builtin_amdgcn_mfma_f32_32x32x16_bf16(xlr, yhc, axy, 0, 0, 0);
            axx = __builtin_amdgcn_mfma_f32_32x32x16_bf16(xlr, xhc, axx, 0, 0, 0);
            ayy = __builtin_amdgcn_mfma_f32_32x32x16_bf16(ylr, yhc, ayy, 0, 0, 0);
        }
    }

    // ---- writeout: verified 32x32 C/D layout: col=lane&31,
    //      row=(reg&3)+8*(reg>>2)+4*(lane>>5) ----
    float* g = grams + (size_t)(b * splitD + c) * 3 * 4096;
    const int col = (qc << 5) + lm;
#pragma unroll
    for (int r = 0; r < 16; ++r) {
        const int row = (qr << 5) + (r & 3) + ((r >> 2) << 3) + ((lane >> 5) << 2);
        g[0 * 4096 + row * 64 + col] = axy[r];
        g[1 * 4096 + row * 64 + col] = axx[r];
        g[2 * 4096 + row * 64 + col] = ayy[r];
    }
}

// ---------------------------------------------------------------------------
// K2: per batch — reduce Gram partials, distances, mean, accumulate.
// ---------------------------------------------------------------------------
__global__ __launch_bounds__(256) void k_gene_dist(const float* __restrict__ grams,
                                                   float* __restrict__ acc,
                                                   int splitD) {
    const int b = blockIdx.x, t = threadIdx.x;
    __shared__ __align__(16) float G[3 * 4096];   // 48 KB
    __shared__ float red[4];

    for (int m = 0; m < 3; ++m) {
#pragma unroll
        for (int k = 0; k < 16; ++k) {
            const int e = t + 256 * k;
            float s = 0.f;
            for (int c = 0; c < splitD; ++c)
                s += grams[((size_t)(b * splitD + c) * 3 + m) * 4096 + e];
            G[m * 4096 + e] = s;
        }
    }
    __syncthreads();

    float local = 0.f;
#pragma unroll
    for (int k = 0; k < 16; ++k) {
        const int e = t + 256 * k;
        const int i = e >> 6, j = e & 63;
        const float gxy = G[e];
        const float gxx = G[4096 + e];
        const float gyy = G[8192 + e];
        const float nxi = G[4096 + i * 65], nxj = G[4096 + j * 65];
        const float nyi = G[8192 + i * 65], nyj = G[8192 + j * 65];
        const float dxy = sqrtf(fmaxf(nxi + nyj - 2.f * gxy, 0.f));
        const float dxx = sqrtf(fmaxf(nxi + nxj - 2.f * gxx, 0.f));
        const float dyy = sqrtf(fmaxf(nyi + nyj - 2.f * gyy, 0.f));
        local += dxy - 0.5f * (dxx + dyy);
    }
#pragma unroll
    for (int off = 32; off; off >>= 1) local += __shfl_down(local, off);
    if ((t & 63) == 0) red[t >> 6] = local;
    __syncthreads();
    if (t == 0) {
        const float bl = red[0] + red[1] + red[2] + red[3];
        atomicAdd(acc, bl * (1.0f / (4096.0f * (float)NB)));
    }
}

// ---------------------------------------------------------------------------
// K2.5: transpose last-NSHARED gene slab -> T[gene][row] (coalesced both sides
// via LDS). blk<128 handles X, else Y. Runs AFTER K2 (reuses gram ws region).
// ---------------------------------------------------------------------------
__global__ __launch_bounds__(256) void k_transpose(const float* __restrict__ X,
                                                   const float* __restrict__ Y,
                                                   float* __restrict__ T) {
    const int blk = blockIdx.x;                       // 0..255
    const float* __restrict__ src = (blk < NB) ? X : Y;
    float* __restrict__ dst = T + (size_t)(blk < NB ? 0 : NSHARED * TOTAL);
    const int rb = (blk & (NB - 1)) * 64;             // row base
    __shared__ float s[NSHARED * 65];
    const int t = threadIdx.x;

#pragma unroll
    for (int it = 0; it < 8; ++it) {
        const int idx = t + 256 * it;                 // 0..2047
        const int r = idx >> 5;                       // 0..63
        const int f = idx & 31;                       // float4 col
        const float4 v = *(const float4*)(src + (size_t)(rb + r) * GENES
                                          + (GENES - NSHARED) + (f << 2));
        s[((f << 2) + 0) * 65 + r] = v.x;
        s[((f << 2) + 1) * 65 + r] = v.y;
        s[((f << 2) + 2) * 65 + r] = v.z;
        s[((f << 2) + 3) * 65 + r] = v.w;
    }
    __syncthreads();

    const int g = t >> 1, h = t & 1;
#pragma unroll
    for (int v = 0; v < 8; ++v) {
        const int r = (h << 5) + (v << 2);
        float4 o;
        o.x = s[g * 65 + r + 0];
        o.y = s[g * 65 + r + 1];
        o.z = s[g * 65 + r + 2];
        o.w = s[g * 65 + r + 3];
        *(float4*)(dst + (size_t)g * TOTAL + rb + r) = o;
    }
}

// ---------------------------------------------------------------------------
// K3: cell-level — one block per shared gene. Reads transposed buffer
// (fully coalesced float4). Clouds: 64 points x 128 dims.
// ---------------------------------------------------------------------------
__global__ __launch_bounds__(256) void k_cell(const float* __restrict__ T,
                                              float* __restrict__ acc) {
    const int s = blockIdx.x;
    const float* __restrict__ tx = T + (size_t)s * TOTAL;
    const float* __restrict__ ty = T + (size_t)(NSHARED + s) * TOTAL;
    const int t = threadIdx.x;

    // cx tile [b][n] at [0..8191], cy at [8192..16383]; reused for Grams after
    __shared__ __align__(16) float lds[16384];    // 64 KB

#pragma unroll
    for (int it = 0; it < 8; ++it) {
        const int i4 = (t + 256 * it) << 2;
        *(float4*)&lds[i4]        = *(const float4*)(tx + i4);
        *(float4*)&lds[8192 + i4] = *(const float4*)(ty + i4);
    }
    __syncthreads();

    const int ti = t & 15, tj = t >> 4;
    const int i0 = ti << 2, j0 = tj << 2;
    float axy[4][4] = {{0}}, axx[4][4] = {{0}}, ayy[4][4] = {{0}};

#pragma unroll 4
    for (int bb = 0; bb < NB; ++bb) {
        const float4 xi4 = *(const float4*)(lds + bb * 64 + i0);
        const float4 xj4 = *(const float4*)(lds + bb * 64 + j0);
        const float4 yi4 = *(const float4*)(lds + 8192 + bb * 64 + i0);
        const float4 yj4 = *(const float4*)(lds + 8192 + bb * 64 + j0);
        const float* xi = &xi4.x;
        const float* xj = &xj4.x;
        const float* yi = &yi4.x;
        const float* yj = &yj4.x;
#pragma unroll
        for (int ii = 0; ii < 4; ++ii) {
#pragma unroll
            for (int jj = 0; jj < 4; ++jj) {
                axy[ii][jj] = fmaf(xi[ii], yj[jj], axy[ii][jj]);
                axx[ii][jj] = fmaf(xi[ii], xj[jj], axx[ii][jj]);
                ayy[ii][jj] = fmaf(yi[ii], yj[jj], ayy[ii][jj]);
            }
        }
    }
    __syncthreads();
    // write Grams into lds[0..12287] (tiles no longer needed)
#pragma unroll
    for (int ii = 0; ii < 4; ++ii) {
        float4 v;
        v.x = axy[ii][0]; v.y = axy[ii][1]; v.z = axy[ii][2]; v.w = axy[ii][3];
        *(float4*)(lds + 0 * 4096 + (i0 + ii) * 64 + j0) = v;
        v.x = axx[ii][0]; v.y = axx[ii][1]; v.z = axx[ii][2]; v.w = axx[ii][3];
        *(float4*)(lds + 1 * 4096 + (i0 + ii) * 64 + j0) = v;
        v.x = ayy[ii][0]; v.y = ayy[ii][1]; v.z = ayy[ii][2]; v.w = ayy[ii][3];
        *(float4*)(lds + 2 * 4096 + (i0 + ii) * 64 + j0) = v;
    }
    __syncthreads();

    float local = 0.f;
#pragma unroll
    for (int k = 0; k < 16; ++k) {
        const int e = t + 256 * k;
        const int i = e >> 6, j = e & 63;
        const float gxy = lds[e];
        const float gxx = lds[4096 + e];
        const float gyy = lds[8192 + e];
        const float nxi = lds[4096 + i * 65], nxj = lds[4096 + j * 65];
        const float nyi = lds[8192 + i * 65], nyj = lds[8192 + j * 65];
        const float dxy = sqrtf(fmaxf(nxi + nyj - 2.f * gxy, 0.f));
        const float dxx = sqrtf(fmaxf(nxi + nxj - 2.f * gxx, 0.f));
        const float dyy = sqrtf(fmaxf(nyi + nyj - 2.f * gyy, 0.f));
        local += dxy - 0.5f * (dxx + dyy);
    }
#pragma unroll
    for (int off = 32; off; off >>= 1) local += __shfl_down(local, off);
    __syncthreads();                 // done reading lds as Grams
    if ((t & 63) == 0) lds[t >> 6] = local;
    __syncthreads();
    if (t == 0) {
        const float bl = lds[0] + lds[1] + lds[2] + lds[3];
        atomicAdd(acc, bl * (1.0f / (4096.0f * (float)NSHARED)));
    }
}

__global__ void k_final(const float* __restrict__ acc, float* __restrict__ out) {
    out[0] = acc[0] + acc[1];
}

extern "C" void kernel_launch(void* const* d_in, const int* in_sizes, int n_in,
                              void* d_out, int out_size, void* d_ws, size_t ws_size,
                              hipStream_t stream) {
    const float* X = (const float*)d_in[0];
    const float* Y = (const float*)d_in[1];
    float* out = (float*)d_out;
    float* ws  = (float*)d_ws;

    // pick splitD (K-slices per batch) so partial-Gram buffer fits in ws
    int splitD = 4;
    while (splitD > 1 &&
           ((size_t)GRAM_OFF + (size_t)splitD * NB * 3 * 4096) * sizeof(float) > ws_size)
        splitD >>= 1;
    const int chunks = (GENES + KC - 1) / KC;            // 79
    const int cper   = (chunks + splitD - 1) / splitD;   // chunks per slice
    const int Dper   = cper * KC;                        // multiple of KC

    float* acc   = ws;
    float* grams = ws + GRAM_OFF;   // also reused as transpose buffer after K2

    hipLaunchKernelGGL(k_zero,           dim3(1),           dim3(64),  0, stream, acc);
    hipLaunchKernelGGL(k_gene_gram_mfma, dim3(NB * splitD), dim3(256), 0, stream,
                       X, Y, grams, splitD, Dper);
    hipLaunchKernelGGL(k_gene_dist,      dim3(NB),          dim3(256), 0, stream,
                       grams, acc + 0, splitD);
    // transpose reuses gram region — stream order guarantees K2 is done
    hipLaunchKernelGGL(k_transpose,      dim3(2 * NB),      dim3(256), 0, stream,
                       X, Y, grams);
    hipLaunchKernelGGL(k_cell,           dim3(NSHARED),     dim3(256), 0, stream,
                       grams, acc + 1);
    hipLaunchKernelGGL(k_final,          dim3(1),           dim3(1),   0, stream, acc, out);
}